// Round 1
// baseline (2072.107 us; speedup 1.0000x reference)
//
#include <hip/hip_runtime.h>
#include <math.h>

#define BS 256
#define LQ 256
#define KN 64
#define BH 512
#define SUB_IN 1537

__device__ __forceinline__ float clip15(float x) {
  return fminf(fmaxf(x, -15.f), 15.f);
}

// out[row] = sum_d X[row*BH + i] * w[i]
__global__ void k_rowdot(const float* __restrict__ X, const float* __restrict__ w,
                         float* __restrict__ out, int rows) {
  int row = blockIdx.x * 4 + (threadIdx.x >> 6);
  int lane = threadIdx.x & 63;
  if (row >= rows) return;
  const float* x = X + (size_t)row * BH;
  float s = 0.f;
#pragma unroll
  for (int i = 0; i < BH; i += 64) s = fmaf(x[i + lane], w[i + lane], s);
#pragma unroll
  for (int off = 32; off; off >>= 1) s += __shfl_down(s, off);
  if (lane == 0) out[row] = s;
}

// 64x64 tile, 256 threads, 4x4 per thread, K-chunk 32
__device__ __forceinline__ void mm32(const float (*As)[68], const float (*Bs)[68],
                                     float acc[4][4], int ty, int tx) {
#pragma unroll
  for (int k = 0; k < 32; ++k) {
    float4 av = *(const float4*)(&As[k][ty * 4]);
    float4 bv = *(const float4*)(&Bs[k][tx * 4]);
    float aa[4] = {av.x, av.y, av.z, av.w};
    float bb[4] = {bv.x, bv.y, bv.z, bv.w};
#pragma unroll
    for (int i = 0; i < 4; ++i)
#pragma unroll
      for (int j = 0; j < 4; ++j)
        acc[i][j] = fmaf(aa[i], bb[j], acc[i][j]);
  }
}

// S[b,c,q] = cw[b,c] + qw[b,q] + sum_d (C[b,c,d]*w4mlu[d])*Q[b,q,d] + bias
__global__ void k_score(const float* __restrict__ C, const float* __restrict__ Q,
                        const float* __restrict__ w4mlu,
                        const float* __restrict__ cw, const float* __restrict__ qw,
                        const float* __restrict__ bias, float* __restrict__ S) {
  const int b = blockIdx.x;
  const int q0 = blockIdx.y * 64;
  const int tid = threadIdx.x;
  const int tx = tid & 15, ty = tid >> 4;
  const int t = tid & 31, r8 = tid >> 5;
  __shared__ __align__(16) float As[32][68];
  __shared__ __align__(16) float Bs[32][68];
  float acc[4][4] = {};
  const float* Cb = C + (size_t)b * KN * BH;
  const float* Qb = Q + (size_t)b * LQ * BH;
  for (int kk = 0; kk < BH; kk += 32) {
    float wm = w4mlu[kk + t];
#pragma unroll
    for (int p = 0; p < 8; ++p) {
      int row = r8 + p * 8;
      As[t][row] = Cb[(size_t)row * BH + kk + t] * wm;
      Bs[t][row] = Qb[(size_t)(q0 + row) * BH + kk + t];
    }
    __syncthreads();
    mm32(As, Bs, acc, ty, tx);
    __syncthreads();
  }
  float bv = bias[0];
#pragma unroll
  for (int i = 0; i < 4; ++i) {
    int c = ty * 4 + i;
    float cwv = cw[b * KN + c] + bv;
#pragma unroll
    for (int j = 0; j < 4; ++j) {
      int q = q0 + tx * 4 + j;
      S[((size_t)b * KN + c) * LQ + q] = acc[i][j] + cwv + qw[b * LQ + q];
    }
  }
}

// softmax over c (64 entries, strided), masked; one thread per q
__global__ void k_softmax_c(const float* __restrict__ S, const float* __restrict__ cmask,
                            float* __restrict__ S2) {
  int b = blockIdx.x;
  int q = threadIdx.x;
  const float* Sb = S + (size_t)b * KN * LQ + q;
  const float* cm = cmask + b * KN;
  float m = -1e30f;
  for (int c = 0; c < KN; ++c) {
    float x = clip15(Sb[(size_t)c * LQ]) * cm[c];
    m = fmaxf(m, x);
  }
  float sum = 0.f;
  for (int c = 0; c < KN; ++c) {
    float mk = cm[c];
    float x = clip15(Sb[(size_t)c * LQ]) * mk;
    sum += __expf(x - m) * mk;
  }
  float inv = 1.f / (sum + 1e-6f);
  for (int c = 0; c < KN; ++c) {
    float mk = cm[c];
    float x = clip15(Sb[(size_t)c * LQ]) * mk;
    S2[((size_t)b * KN + c) * LQ + q] = __expf(x - m) * mk * inv;
  }
}

// softmax over q (row of 256), masked, in place; one wave per row
__global__ void k_softmax_q(float* __restrict__ S, const float* __restrict__ qmask) {
  int row = blockIdx.x * 4 + (threadIdx.x >> 6);  // b*KN + c
  int lane = threadIdx.x & 63;
  int b = row >> 6;
  float4* Sr = (float4*)(S + (size_t)row * LQ);
  const float4* Qm = (const float4*)(qmask + (size_t)b * LQ);
  float4 xv = Sr[lane];
  float4 mv = Qm[lane];
  float xa[4] = {xv.x, xv.y, xv.z, xv.w};
  float ma[4] = {mv.x, mv.y, mv.z, mv.w};
  float m = -1e30f;
#pragma unroll
  for (int j = 0; j < 4; ++j) { xa[j] = clip15(xa[j]) * ma[j]; m = fmaxf(m, xa[j]); }
#pragma unroll
  for (int off = 32; off; off >>= 1) m = fmaxf(m, __shfl_xor(m, off));
  float s = 0.f;
#pragma unroll
  for (int j = 0; j < 4; ++j) { xa[j] = __expf(xa[j] - m) * ma[j]; s += xa[j]; }
#pragma unroll
  for (int off = 32; off; off >>= 1) s += __shfl_xor(s, off);
  float inv = 1.f / (s + 1e-6f);
  Sr[lane] = make_float4(xa[0] * inv, xa[1] * inv, xa[2] * inv, xa[3] * inv);
}

// A[b,c,d] = sum_q S1[b,c,q] * Q[b,q,d]
__global__ void k_gemm_A(const float* __restrict__ S1, const float* __restrict__ Q,
                         float* __restrict__ A) {
  const int b = blockIdx.x;
  const int d0 = blockIdx.y * 64;
  const int tid = threadIdx.x;
  const int tx = tid & 15, ty = tid >> 4;
  const int t = tid & 31, r8 = tid >> 5;
  const int ol = tid & 63, r4 = tid >> 6;
  __shared__ __align__(16) float As[32][68];
  __shared__ __align__(16) float Bs[32][68];
  float acc[4][4] = {};
  const float* S1b = S1 + (size_t)b * KN * LQ;
  const float* Qb = Q + (size_t)b * LQ * BH;
  for (int kk = 0; kk < LQ; kk += 32) {
#pragma unroll
    for (int p = 0; p < 8; ++p) {
      int c = r8 + p * 8;
      As[t][c] = S1b[(size_t)c * LQ + kk + t];
    }
#pragma unroll
    for (int p = 0; p < 8; ++p) {
      int kr = r4 + p * 4;
      Bs[kr][ol] = Qb[(size_t)(kk + kr) * BH + d0 + ol];
    }
    __syncthreads();
    mm32(As, Bs, acc, ty, tx);
    __syncthreads();
  }
#pragma unroll
  for (int i = 0; i < 4; ++i) {
    int c = ty * 4 + i;
#pragma unroll
    for (int j = 0; j < 4; ++j)
      A[((size_t)b * KN + c) * BH + d0 + tx * 4 + j] = acc[i][j];
  }
}

// T[b,c,k] = sum_q S1[b,c,q] * S2[b,k,q]
__global__ void k_gemm_T(const float* __restrict__ S1, const float* __restrict__ S2,
                         float* __restrict__ T) {
  const int b = blockIdx.x;
  const int tid = threadIdx.x;
  const int tx = tid & 15, ty = tid >> 4;
  const int t = tid & 31, r8 = tid >> 5;
  __shared__ __align__(16) float As[32][68];
  __shared__ __align__(16) float Bs[32][68];
  float acc[4][4] = {};
  const float* S1b = S1 + (size_t)b * KN * LQ;
  const float* S2b = S2 + (size_t)b * KN * LQ;
  for (int kk = 0; kk < LQ; kk += 32) {
#pragma unroll
    for (int p = 0; p < 8; ++p) {
      int c = r8 + p * 8;
      As[t][c] = S1b[(size_t)c * LQ + kk + t];
      Bs[t][c] = S2b[(size_t)c * LQ + kk + t];
    }
    __syncthreads();
    mm32(As, Bs, acc, ty, tx);
    __syncthreads();
  }
#pragma unroll
  for (int i = 0; i < 4; ++i) {
    int c = ty * 4 + i;
#pragma unroll
    for (int j = 0; j < 4; ++j)
      T[((size_t)b * KN + c) * KN + tx * 4 + j] = acc[i][j];
  }
}

// B[b,c,d] = sum_k T[b,c,k] * C[b,k,d]
__global__ void k_gemm_B(const float* __restrict__ T, const float* __restrict__ C,
                         float* __restrict__ Bout) {
  const int b = blockIdx.x;
  const int d0 = blockIdx.y * 64;
  const int tid = threadIdx.x;
  const int tx = tid & 15, ty = tid >> 4;
  const int t = tid & 31, r8 = tid >> 5;
  const int ol = tid & 63, r4 = tid >> 6;
  __shared__ __align__(16) float As[32][68];
  __shared__ __align__(16) float Bs[32][68];
  float acc[4][4] = {};
  const float* Tb = T + (size_t)b * KN * KN;
  const float* Cb = C + (size_t)b * KN * BH;
  for (int kk = 0; kk < KN; kk += 32) {
#pragma unroll
    for (int p = 0; p < 8; ++p) {
      int c = r8 + p * 8;
      As[t][c] = Tb[(size_t)c * KN + kk + t];
    }
#pragma unroll
    for (int p = 0; p < 8; ++p) {
      int kr = r4 + p * 4;
      Bs[kr][ol] = Cb[(size_t)(kk + kr) * BH + d0 + ol];
    }
    __syncthreads();
    mm32(As, Bs, acc, ty, tx);
    __syncthreads();
  }
#pragma unroll
  for (int i = 0; i < 4; ++i) {
    int c = ty * 4 + i;
#pragma unroll
    for (int j = 0; j < 4; ++j)
      Bout[((size_t)b * KN + c) * BH + d0 + tx * 4 + j] = acc[i][j];
  }
}

// H[b,c,o] = sum_j concat(C, A, C*A, C*B)[b,c,j] * prj[j,o]
__global__ void k_proj(const float* __restrict__ C, const float* __restrict__ A,
                       const float* __restrict__ Bm, const float* __restrict__ prj,
                       float* __restrict__ H) {
  const int b = blockIdx.x;
  const int o0 = blockIdx.y * 64;
  const int tid = threadIdx.x;
  const int tx = tid & 15, ty = tid >> 4;
  const int t = tid & 31, r8 = tid >> 5;
  const int ol = tid & 63, r4 = tid >> 6;
  __shared__ __align__(16) float As[32][68];
  __shared__ __align__(16) float Bs[32][68];
  float acc[4][4] = {};
  const float* Cb = C + (size_t)b * KN * BH;
  const float* Ab = A + (size_t)b * KN * BH;
  const float* Bb = Bm + (size_t)b * KN * BH;
  for (int kk = 0; kk < 4 * BH; kk += 32) {
    int seg = kk >> 9;
    int dd = (kk & 511) + t;
#pragma unroll
    for (int p = 0; p < 8; ++p) {
      int c = r8 + p * 8;
      size_t idx = (size_t)c * BH + dd;
      float v;
      if (seg == 0) v = Cb[idx];
      else if (seg == 1) v = Ab[idx];
      else if (seg == 2) v = Cb[idx] * Ab[idx];
      else v = Cb[idx] * Bb[idx];
      As[t][c] = v;
    }
#pragma unroll
    for (int p = 0; p < 8; ++p) {
      int kr = r4 + p * 4;
      Bs[kr][ol] = prj[(size_t)(kk + kr) * BH + o0 + ol];
    }
    __syncthreads();
    mm32(As, Bs, acc, ty, tx);
    __syncthreads();
  }
#pragma unroll
  for (int i = 0; i < 4; ++i) {
    int c = ty * 4 + i;
#pragma unroll
    for (int j = 0; j < 4; ++j)
      H[((size_t)b * KN + c) * BH + o0 + tx * 4 + j] = acc[i][j];
  }
}

// out[b,kb,o] = sum_s x[b,s]*W[kb,s,o] + blk_b[kb,o];
// x = [Hno[b,kb,:], Hna[b,kb,:], C[b,kb,:], rewards[b]]
__global__ void k_blk(const float* __restrict__ Hno, const float* __restrict__ Hna,
                      const float* __restrict__ C, const float* __restrict__ rew,
                      const float* __restrict__ W, const float* __restrict__ bias,
                      float* __restrict__ out) {
  const int kb = blockIdx.x;       // node block
  const int b0 = blockIdx.y * 64;  // batch tile
  const int o0 = blockIdx.z * 64;  // output tile
  const int tid = threadIdx.x;
  const int tx = tid & 15, ty = tid >> 4;
  const int t = tid & 31, r8 = tid >> 5;
  const int ol = tid & 63, r4 = tid >> 6;
  __shared__ __align__(16) float As[32][68];
  __shared__ __align__(16) float Bs[32][68];
  float acc[4][4] = {};
  const float* Wk = W + (size_t)kb * SUB_IN * BH;
  for (int kk = 0; kk < 1536; kk += 32) {
    int seg = kk >> 9;
    int dd = (kk & 511) + t;
    const float* src = (seg == 0) ? Hno : (seg == 1) ? Hna : C;
#pragma unroll
    for (int p = 0; p < 8; ++p) {
      int bb = r8 + p * 8;
      As[t][bb] = src[((size_t)(b0 + bb) * KN + kb) * BH + dd];
    }
#pragma unroll
    for (int p = 0; p < 8; ++p) {
      int kr = r4 + p * 4;
      Bs[kr][ol] = Wk[(size_t)(kk + kr) * BH + o0 + ol];
    }
    __syncthreads();
    mm32(As, Bs, acc, ty, tx);
    __syncthreads();
  }
#pragma unroll
  for (int i = 0; i < 4; ++i) {
    int b = b0 + ty * 4 + i;
    float rv = rew[b];
#pragma unroll
    for (int j = 0; j < 4; ++j) {
      int o = o0 + tx * 4 + j;
      out[((size_t)b * KN + kb) * BH + o] =
          acc[i][j] + rv * Wk[(size_t)1536 * BH + o] + bias[kb * BH + o];
    }
  }
}

extern "C" void kernel_launch(void* const* d_in, const int* in_sizes, int n_in,
                              void* d_out, int out_size, void* d_ws, size_t ws_size,
                              hipStream_t stream) {
  (void)in_sizes; (void)n_in; (void)out_size; (void)ws_size;
  const float* act   = (const float*)d_in[0];
  const float* obs   = (const float*)d_in[1];
  const float* amask = (const float*)d_in[2];
  const float* omask = (const float*)d_in[3];
  const float* rew   = (const float*)d_in[4];
  const float* node  = (const float*)d_in[5];
  const float* nmask = (const float*)d_in[6];
  const float* w4C_o = (const float*)d_in[7];
  const float* w4Q_o = (const float*)d_in[8];
  const float* w4m_o = (const float*)d_in[9];
  const float* bias_o= (const float*)d_in[10];
  const float* w4C_a = (const float*)d_in[11];
  const float* w4Q_a = (const float*)d_in[12];
  const float* w4m_a = (const float*)d_in[13];
  const float* bias_a= (const float*)d_in[14];
  const float* prj_o = (const float*)d_in[15];
  const float* prj_a = (const float*)d_in[16];
  const float* blkW  = (const float*)d_in[17];
  const float* blkb  = (const float*)d_in[18];
  float* out = (float*)d_out;

  float* ws = (float*)d_ws;
  size_t off = 0;
  float* cw  = ws + off; off += BS * KN;
  float* qw  = ws + off; off += BS * LQ;
  float* S   = ws + off; off += (size_t)BS * KN * LQ;   // becomes S1 in place
  float* S2  = ws + off; off += (size_t)BS * KN * LQ;
  float* A   = ws + off; off += (size_t)BS * KN * BH;
  float* T   = ws + off; off += (size_t)BS * KN * KN;
  float* Bm  = ws + off; off += (size_t)BS * KN * BH;
  float* Hno = ws + off; off += (size_t)BS * KN * BH;
  float* Hna = ws + off; off += (size_t)BS * KN * BH;
  // total ~172 MB of workspace

  for (int head = 0; head < 2; ++head) {
    const float* Qseq  = head ? act : obs;
    const float* qmask = head ? amask : omask;
    const float* w4C   = head ? w4C_a : w4C_o;
    const float* w4Q   = head ? w4Q_a : w4Q_o;
    const float* w4m   = head ? w4m_a : w4m_o;
    const float* bias  = head ? bias_a : bias_o;
    const float* prj   = head ? prj_a : prj_o;
    float* H = head ? Hna : Hno;

    k_rowdot<<<dim3(BS * KN / 4), 256, 0, stream>>>(node, w4C, cw, BS * KN);
    k_rowdot<<<dim3(BS * LQ / 4), 256, 0, stream>>>(Qseq, w4Q, qw, BS * LQ);
    k_score<<<dim3(BS, LQ / 64), 256, 0, stream>>>(node, Qseq, w4m, cw, qw, bias, S);
    k_softmax_c<<<dim3(BS), 256, 0, stream>>>(S, nmask, S2);   // must precede in-place S1
    k_softmax_q<<<dim3(BS * KN / 4), 256, 0, stream>>>(S, qmask);
    k_gemm_A<<<dim3(BS, BH / 64), 256, 0, stream>>>(S, Qseq, A);
    k_gemm_T<<<dim3(BS), 256, 0, stream>>>(S, S2, T);
    k_gemm_B<<<dim3(BS, BH / 64), 256, 0, stream>>>(T, node, Bm);
    k_proj<<<dim3(BS, BH / 64), 256, 0, stream>>>(node, A, Bm, prj, H);
  }
  k_blk<<<dim3(KN, BS / 64, BH / 64), 256, 0, stream>>>(Hno, Hna, node, rew, blkW, blkb, out);
}

// Round 2
// 863.972 us; speedup vs baseline: 2.3984x; 2.3984x over previous
//
#include <hip/hip_runtime.h>
#include <math.h>

#define BS 256
#define LQ 256
#define KN 64
#define BH 512
#define SUB_IN 1537

typedef __attribute__((ext_vector_type(8))) short bf16x8;
typedef __attribute__((ext_vector_type(4))) float f32x4;

__device__ __forceinline__ float clip15(float x) {
  return fminf(fmaxf(x, -15.f), 15.f);
}

// f32 -> bf16 (RNE), as raw short
__device__ __forceinline__ short f2bf(float f) {
  unsigned u = __float_as_uint(f);
  u = u + 0x7fffu + ((u >> 16) & 1u);
  return (short)(u >> 16);
}

// XOR swizzle: permute the 16B slot within each 128B row by a bijection of row
#define SWZ(row, byte) ((byte) ^ (((((row) ^ ((row) >> 3)) & 7)) << 4))

// ---------------- f32 helper kernels (unchanged numerics path) ----------------

__global__ void k_rowdot(const float* __restrict__ X, const float* __restrict__ w,
                         float* __restrict__ out, int rows) {
  int row = blockIdx.x * 4 + (threadIdx.x >> 6);
  int lane = threadIdx.x & 63;
  if (row >= rows) return;
  const float* x = X + (size_t)row * BH;
  float s = 0.f;
#pragma unroll
  for (int i = 0; i < BH; i += 64) s = fmaf(x[i + lane], w[i + lane], s);
#pragma unroll
  for (int off = 32; off; off >>= 1) s += __shfl_down(s, off);
  if (lane == 0) out[row] = s;
}

__device__ __forceinline__ void mm32(const float (*As)[68], const float (*Bs)[68],
                                     float acc[4][4], int ty, int tx) {
#pragma unroll
  for (int k = 0; k < 32; ++k) {
    float4 av = *(const float4*)(&As[k][ty * 4]);
    float4 bv = *(const float4*)(&Bs[k][tx * 4]);
    float aa[4] = {av.x, av.y, av.z, av.w};
    float bb[4] = {bv.x, bv.y, bv.z, bv.w};
#pragma unroll
    for (int i = 0; i < 4; ++i)
#pragma unroll
      for (int j = 0; j < 4; ++j)
        acc[i][j] = fmaf(aa[i], bb[j], acc[i][j]);
  }
}

__global__ void k_score(const float* __restrict__ C, const float* __restrict__ Q,
                        const float* __restrict__ w4mlu,
                        const float* __restrict__ cw, const float* __restrict__ qw,
                        const float* __restrict__ bias, float* __restrict__ S) {
  const int b = blockIdx.x;
  const int q0 = blockIdx.y * 64;
  const int tid = threadIdx.x;
  const int tx = tid & 15, ty = tid >> 4;
  const int t = tid & 31, r8 = tid >> 5;
  __shared__ __align__(16) float As[32][68];
  __shared__ __align__(16) float Bs[32][68];
  float acc[4][4] = {};
  const float* Cb = C + (size_t)b * KN * BH;
  const float* Qb = Q + (size_t)b * LQ * BH;
  for (int kk = 0; kk < BH; kk += 32) {
    float wm = w4mlu[kk + t];
#pragma unroll
    for (int p = 0; p < 8; ++p) {
      int row = r8 + p * 8;
      As[t][row] = Cb[(size_t)row * BH + kk + t] * wm;
      Bs[t][row] = Qb[(size_t)(q0 + row) * BH + kk + t];
    }
    __syncthreads();
    mm32(As, Bs, acc, ty, tx);
    __syncthreads();
  }
  float bv = bias[0];
#pragma unroll
  for (int i = 0; i < 4; ++i) {
    int c = ty * 4 + i;
    float cwv = cw[b * KN + c] + bv;
#pragma unroll
    for (int j = 0; j < 4; ++j) {
      int q = q0 + tx * 4 + j;
      S[((size_t)b * KN + c) * LQ + q] = acc[i][j] + cwv + qw[b * LQ + q];
    }
  }
}

__global__ void k_softmax_c(const float* __restrict__ S, const float* __restrict__ cmask,
                            float* __restrict__ S2) {
  int b = blockIdx.x;
  int q = threadIdx.x;
  const float* Sb = S + (size_t)b * KN * LQ + q;
  const float* cm = cmask + b * KN;
  float m = -1e30f;
  for (int c = 0; c < KN; ++c) {
    float x = clip15(Sb[(size_t)c * LQ]) * cm[c];
    m = fmaxf(m, x);
  }
  float sum = 0.f;
  for (int c = 0; c < KN; ++c) {
    float mk = cm[c];
    float x = clip15(Sb[(size_t)c * LQ]) * mk;
    sum += __expf(x - m) * mk;
  }
  float inv = 1.f / (sum + 1e-6f);
  for (int c = 0; c < KN; ++c) {
    float mk = cm[c];
    float x = clip15(Sb[(size_t)c * LQ]) * mk;
    S2[((size_t)b * KN + c) * LQ + q] = __expf(x - m) * mk * inv;
  }
}

__global__ void k_softmax_q(float* __restrict__ S, const float* __restrict__ qmask) {
  int row = blockIdx.x * 4 + (threadIdx.x >> 6);
  int lane = threadIdx.x & 63;
  int b = row >> 6;
  float4* Sr = (float4*)(S + (size_t)row * LQ);
  const float4* Qm = (const float4*)(qmask + (size_t)b * LQ);
  float4 xv = Sr[lane];
  float4 mv = Qm[lane];
  float xa[4] = {xv.x, xv.y, xv.z, xv.w};
  float ma[4] = {mv.x, mv.y, mv.z, mv.w};
  float m = -1e30f;
#pragma unroll
  for (int j = 0; j < 4; ++j) { xa[j] = clip15(xa[j]) * ma[j]; m = fmaxf(m, xa[j]); }
#pragma unroll
  for (int off = 32; off; off >>= 1) m = fmaxf(m, __shfl_xor(m, off));
  float s = 0.f;
#pragma unroll
  for (int j = 0; j < 4; ++j) { xa[j] = __expf(xa[j] - m) * ma[j]; s += xa[j]; }
#pragma unroll
  for (int off = 32; off; off >>= 1) s += __shfl_xor(s, off);
  float inv = 1.f / (s + 1e-6f);
  Sr[lane] = make_float4(xa[0] * inv, xa[1] * inv, xa[2] * inv, xa[3] * inv);
}

__global__ void k_gemm_A(const float* __restrict__ S1, const float* __restrict__ Q,
                         float* __restrict__ A) {
  const int b = blockIdx.x;
  const int d0 = blockIdx.y * 64;
  const int tid = threadIdx.x;
  const int tx = tid & 15, ty = tid >> 4;
  const int t = tid & 31, r8 = tid >> 5;
  const int ol = tid & 63, r4 = tid >> 6;
  __shared__ __align__(16) float As[32][68];
  __shared__ __align__(16) float Bs[32][68];
  float acc[4][4] = {};
  const float* S1b = S1 + (size_t)b * KN * LQ;
  const float* Qb = Q + (size_t)b * LQ * BH;
  for (int kk = 0; kk < LQ; kk += 32) {
#pragma unroll
    for (int p = 0; p < 8; ++p) {
      int c = r8 + p * 8;
      As[t][c] = S1b[(size_t)c * LQ + kk + t];
    }
#pragma unroll
    for (int p = 0; p < 8; ++p) {
      int kr = r4 + p * 4;
      Bs[kr][ol] = Qb[(size_t)(kk + kr) * BH + d0 + ol];
    }
    __syncthreads();
    mm32(As, Bs, acc, ty, tx);
    __syncthreads();
  }
#pragma unroll
  for (int i = 0; i < 4; ++i) {
    int c = ty * 4 + i;
#pragma unroll
    for (int j = 0; j < 4; ++j)
      A[((size_t)b * KN + c) * BH + d0 + tx * 4 + j] = acc[i][j];
  }
}

__global__ void k_gemm_T(const float* __restrict__ S1, const float* __restrict__ S2,
                         float* __restrict__ T) {
  const int b = blockIdx.x;
  const int tid = threadIdx.x;
  const int tx = tid & 15, ty = tid >> 4;
  const int t = tid & 31, r8 = tid >> 5;
  __shared__ __align__(16) float As[32][68];
  __shared__ __align__(16) float Bs[32][68];
  float acc[4][4] = {};
  const float* S1b = S1 + (size_t)b * KN * LQ;
  const float* S2b = S2 + (size_t)b * KN * LQ;
  for (int kk = 0; kk < LQ; kk += 32) {
#pragma unroll
    for (int p = 0; p < 8; ++p) {
      int c = r8 + p * 8;
      As[t][c] = S1b[(size_t)c * LQ + kk + t];
      Bs[t][c] = S2b[(size_t)c * LQ + kk + t];
    }
    __syncthreads();
    mm32(As, Bs, acc, ty, tx);
    __syncthreads();
  }
#pragma unroll
  for (int i = 0; i < 4; ++i) {
    int c = ty * 4 + i;
#pragma unroll
    for (int j = 0; j < 4; ++j)
      T[((size_t)b * KN + c) * KN + tx * 4 + j] = acc[i][j];
  }
}

__global__ void k_gemm_B(const float* __restrict__ T, const float* __restrict__ C,
                         float* __restrict__ Bout) {
  const int b = blockIdx.x;
  const int d0 = blockIdx.y * 64;
  const int tid = threadIdx.x;
  const int tx = tid & 15, ty = tid >> 4;
  const int t = tid & 31, r8 = tid >> 5;
  const int ol = tid & 63, r4 = tid >> 6;
  __shared__ __align__(16) float As[32][68];
  __shared__ __align__(16) float Bs[32][68];
  float acc[4][4] = {};
  const float* Tb = T + (size_t)b * KN * KN;
  const float* Cb = C + (size_t)b * KN * BH;
  for (int kk = 0; kk < KN; kk += 32) {
#pragma unroll
    for (int p = 0; p < 8; ++p) {
      int c = r8 + p * 8;
      As[t][c] = Tb[(size_t)c * KN + kk + t];
    }
#pragma unroll
    for (int p = 0; p < 8; ++p) {
      int kr = r4 + p * 4;
      Bs[kr][ol] = Cb[(size_t)(kk + kr) * BH + d0 + ol];
    }
    __syncthreads();
    mm32(As, Bs, acc, ty, tx);
    __syncthreads();
  }
#pragma unroll
  for (int i = 0; i < 4; ++i) {
    int c = ty * 4 + i;
#pragma unroll
    for (int j = 0; j < 4; ++j)
      Bout[((size_t)b * KN + c) * BH + d0 + tx * 4 + j] = acc[i][j];
  }
}

// ---------------- MFMA bf16 kernels for the two dominant GEMMs ----------------

// H[b,c,o] = sum_j feat[b,c,j] * prj[j,o]; feat = concat(C, A, C*A, C*B) along j
__global__ void k_proj_mfma(const float* __restrict__ C, const float* __restrict__ A,
                            const float* __restrict__ Bm, const float* __restrict__ prj,
                            float* __restrict__ H) {
  const int b = blockIdx.x;
  const int o0 = blockIdx.y * 64;
  const int tid = threadIdx.x;
  __shared__ __align__(16) short As[64 * 64];
  __shared__ __align__(16) short Bs[64 * 64];
  f32x4 acc[4] = {};
  const float* Cb = C + (size_t)b * KN * BH;
  const float* Ab = A + (size_t)b * KN * BH;
  const float* Bb = Bm + (size_t)b * KN * BH;
  const int kl = (tid & 15) * 4;      // A-stage k offset
  const int n0 = (tid & 15) * 4;      // B-stage n block
  const int k0 = (tid >> 4) * 4;      // B-stage k block
  const int wave = tid >> 6, lane = tid & 63;
  const int m0 = wave * 16;

  for (int kk = 0; kk < 4 * BH; kk += 64) {
    const int seg = kk >> 9;
    const int d0 = (kk & 511);
    const float* p0 = (seg == 1) ? Ab : Cb;
    const float* p1 = (seg == 2) ? Ab : Bb;
    const int mul = (seg >= 2);
    // ---- stage A tile: feat rows c=0..63, k=0..63 (bf16, swizzled) ----
#pragma unroll
    for (int it = 0; it < 4; ++it) {
      int row = (tid >> 4) + it * 16;
      size_t gidx = (size_t)row * BH + d0 + kl;
      f32x4 v = *(const f32x4*)(p0 + gidx);
      if (mul) {
        f32x4 w = *(const f32x4*)(p1 + gidx);
        v = v * w;
      }
      int byte = SWZ(row, row * 128 + kl * 2);
      *(short4*)((char*)As + byte) =
          make_short4(f2bf(v.x), f2bf(v.y), f2bf(v.z), f2bf(v.w));
    }
    // ---- stage B tile transposed: Bs[n][k] from prj[kk+k][o0+n] ----
    {
      f32x4 r0 = *(const f32x4*)(prj + (size_t)(kk + k0 + 0) * BH + o0 + n0);
      f32x4 r1 = *(const f32x4*)(prj + (size_t)(kk + k0 + 1) * BH + o0 + n0);
      f32x4 r2 = *(const f32x4*)(prj + (size_t)(kk + k0 + 2) * BH + o0 + n0);
      f32x4 r3 = *(const f32x4*)(prj + (size_t)(kk + k0 + 3) * BH + o0 + n0);
#pragma unroll
      for (int j = 0; j < 4; ++j) {
        int n = n0 + j;
        float a0 = (j == 0) ? r0.x : (j == 1) ? r0.y : (j == 2) ? r0.z : r0.w;
        float a1 = (j == 0) ? r1.x : (j == 1) ? r1.y : (j == 2) ? r1.z : r1.w;
        float a2 = (j == 0) ? r2.x : (j == 1) ? r2.y : (j == 2) ? r2.z : r2.w;
        float a3 = (j == 0) ? r3.x : (j == 1) ? r3.y : (j == 2) ? r3.z : r3.w;
        int byte = SWZ(n, n * 128 + k0 * 2);
        *(short4*)((char*)Bs + byte) =
            make_short4(f2bf(a0), f2bf(a1), f2bf(a2), f2bf(a3));
      }
    }
    __syncthreads();
    // ---- MFMA: wave computes rows m0..m0+15 x all 64 cols ----
#pragma unroll
    for (int kb = 0; kb < 2; ++kb) {
      int kb16 = kb * 32 + (lane >> 4) * 8;
      int arow = m0 + (lane & 15);
      bf16x8 af = *(const bf16x8*)((const char*)As + SWZ(arow, arow * 128 + kb16 * 2));
#pragma unroll
      for (int f = 0; f < 4; ++f) {
        int nrow = f * 16 + (lane & 15);
        bf16x8 bfr = *(const bf16x8*)((const char*)Bs + SWZ(nrow, nrow * 128 + kb16 * 2));
        acc[f] = __builtin_amdgcn_mfma_f32_16x16x32_bf16(af, bfr, acc[f], 0, 0, 0);
      }
    }
    __syncthreads();
  }
#pragma unroll
  for (int f = 0; f < 4; ++f) {
#pragma unroll
    for (int e = 0; e < 4; ++e) {
      int c = m0 + (lane >> 4) * 4 + e;
      int o = o0 + f * 16 + (lane & 15);
      H[((size_t)b * KN + c) * BH + o] = acc[f][e];
    }
  }
}

// out[b,kb,o] = sum_s x[b,kb,s] * W[kb,s,o] + rew[b]*W[kb,1536,o] + bias[kb,o]
// x = [Hno, Hna, node] segments of 512
__global__ void k_blk_mfma(const float* __restrict__ Hno, const float* __restrict__ Hna,
                           const float* __restrict__ C, const float* __restrict__ rew,
                           const float* __restrict__ W, const float* __restrict__ bias,
                           float* __restrict__ out) {
  const int kb = blockIdx.x;
  const int b0 = blockIdx.y * 64;
  const int o0 = blockIdx.z * 64;
  const int tid = threadIdx.x;
  __shared__ __align__(16) short As[64 * 64];
  __shared__ __align__(16) short Bs[64 * 64];
  f32x4 acc[4] = {};
  const float* Wk = W + (size_t)kb * SUB_IN * BH;
  const int kl = (tid & 15) * 4;
  const int n0 = (tid & 15) * 4;
  const int k0 = (tid >> 4) * 4;
  const int wave = tid >> 6, lane = tid & 63;
  const int m0 = wave * 16;

  for (int kk = 0; kk < 1536; kk += 64) {
    const int seg = kk >> 9;
    const int d0 = (kk & 511);
    const float* src = (seg == 0) ? Hno : (seg == 1) ? Hna : C;
    // ---- stage A tile: rows = batch b0..b0+63 ----
#pragma unroll
    for (int it = 0; it < 4; ++it) {
      int row = (tid >> 4) + it * 16;
      size_t gidx = ((size_t)(b0 + row) * KN + kb) * BH + d0 + kl;
      f32x4 v = *(const f32x4*)(src + gidx);
      int byte = SWZ(row, row * 128 + kl * 2);
      *(short4*)((char*)As + byte) =
          make_short4(f2bf(v.x), f2bf(v.y), f2bf(v.z), f2bf(v.w));
    }
    // ---- stage B tile transposed from Wk ----
    {
      f32x4 r0 = *(const f32x4*)(Wk + (size_t)(kk + k0 + 0) * BH + o0 + n0);
      f32x4 r1 = *(const f32x4*)(Wk + (size_t)(kk + k0 + 1) * BH + o0 + n0);
      f32x4 r2 = *(const f32x4*)(Wk + (size_t)(kk + k0 + 2) * BH + o0 + n0);
      f32x4 r3 = *(const f32x4*)(Wk + (size_t)(kk + k0 + 3) * BH + o0 + n0);
#pragma unroll
      for (int j = 0; j < 4; ++j) {
        int n = n0 + j;
        float a0 = (j == 0) ? r0.x : (j == 1) ? r0.y : (j == 2) ? r0.z : r0.w;
        float a1 = (j == 0) ? r1.x : (j == 1) ? r1.y : (j == 2) ? r1.z : r1.w;
        float a2 = (j == 0) ? r2.x : (j == 1) ? r2.y : (j == 2) ? r2.z : r2.w;
        float a3 = (j == 0) ? r3.x : (j == 1) ? r3.y : (j == 2) ? r3.z : r3.w;
        int byte = SWZ(n, n * 128 + k0 * 2);
        *(short4*)((char*)Bs + byte) =
            make_short4(f2bf(a0), f2bf(a1), f2bf(a2), f2bf(a3));
      }
    }
    __syncthreads();
#pragma unroll
    for (int kb2 = 0; kb2 < 2; ++kb2) {
      int kb16 = kb2 * 32 + (lane >> 4) * 8;
      int arow = m0 + (lane & 15);
      bf16x8 af = *(const bf16x8*)((const char*)As + SWZ(arow, arow * 128 + kb16 * 2));
#pragma unroll
      for (int f = 0; f < 4; ++f) {
        int nrow = f * 16 + (lane & 15);
        bf16x8 bfr = *(const bf16x8*)((const char*)Bs + SWZ(nrow, nrow * 128 + kb16 * 2));
        acc[f] = __builtin_amdgcn_mfma_f32_16x16x32_bf16(af, bfr, acc[f], 0, 0, 0);
      }
    }
    __syncthreads();
  }
#pragma unroll
  for (int f = 0; f < 4; ++f) {
    int o = o0 + f * 16 + (lane & 15);
    float wr = Wk[(size_t)1536 * BH + o];
    float bv = bias[kb * BH + o];
#pragma unroll
    for (int e = 0; e < 4; ++e) {
      int bb = b0 + m0 + (lane >> 4) * 4 + e;
      out[((size_t)bb * KN + kb) * BH + o] = acc[f][e] + rew[bb] * wr + bv;
    }
  }
}

extern "C" void kernel_launch(void* const* d_in, const int* in_sizes, int n_in,
                              void* d_out, int out_size, void* d_ws, size_t ws_size,
                              hipStream_t stream) {
  (void)in_sizes; (void)n_in; (void)out_size; (void)ws_size;
  const float* act   = (const float*)d_in[0];
  const float* obs   = (const float*)d_in[1];
  const float* amask = (const float*)d_in[2];
  const float* omask = (const float*)d_in[3];
  const float* rew   = (const float*)d_in[4];
  const float* node  = (const float*)d_in[5];
  const float* nmask = (const float*)d_in[6];
  const float* w4C_o = (const float*)d_in[7];
  const float* w4Q_o = (const float*)d_in[8];
  const float* w4m_o = (const float*)d_in[9];
  const float* bias_o= (const float*)d_in[10];
  const float* w4C_a = (const float*)d_in[11];
  const float* w4Q_a = (const float*)d_in[12];
  const float* w4m_a = (const float*)d_in[13];
  const float* bias_a= (const float*)d_in[14];
  const float* prj_o = (const float*)d_in[15];
  const float* prj_a = (const float*)d_in[16];
  const float* blkW  = (const float*)d_in[17];
  const float* blkb  = (const float*)d_in[18];
  float* out = (float*)d_out;

  float* ws = (float*)d_ws;
  size_t off = 0;
  float* cw  = ws + off; off += BS * KN;
  float* qw  = ws + off; off += BS * LQ;
  float* S   = ws + off; off += (size_t)BS * KN * LQ;   // becomes S1 in place
  float* S2  = ws + off; off += (size_t)BS * KN * LQ;
  float* A   = ws + off; off += (size_t)BS * KN * BH;
  float* T   = ws + off; off += (size_t)BS * KN * KN;
  float* Bm  = ws + off; off += (size_t)BS * KN * BH;
  float* Hno = ws + off; off += (size_t)BS * KN * BH;
  float* Hna = ws + off; off += (size_t)BS * KN * BH;

  for (int head = 0; head < 2; ++head) {
    const float* Qseq  = head ? act : obs;
    const float* qmask = head ? amask : omask;
    const float* w4C   = head ? w4C_a : w4C_o;
    const float* w4Q   = head ? w4Q_a : w4Q_o;
    const float* w4m   = head ? w4m_a : w4m_o;
    const float* bias  = head ? bias_a : bias_o;
    const float* prj   = head ? prj_a : prj_o;
    float* H = head ? Hna : Hno;

    k_rowdot<<<dim3(BS * KN / 4), 256, 0, stream>>>(node, w4C, cw, BS * KN);
    k_rowdot<<<dim3(BS * LQ / 4), 256, 0, stream>>>(Qseq, w4Q, qw, BS * LQ);
    k_score<<<dim3(BS, LQ / 64), 256, 0, stream>>>(node, Qseq, w4m, cw, qw, bias, S);
    k_softmax_c<<<dim3(BS), 256, 0, stream>>>(S, nmask, S2);   // must precede in-place S1
    k_softmax_q<<<dim3(BS * KN / 4), 256, 0, stream>>>(S, qmask);
    k_gemm_A<<<dim3(BS, BH / 64), 256, 0, stream>>>(S, Qseq, A);
    k_gemm_T<<<dim3(BS), 256, 0, stream>>>(S, S2, T);
    k_gemm_B<<<dim3(BS, BH / 64), 256, 0, stream>>>(T, node, Bm);
    k_proj_mfma<<<dim3(BS, BH / 64), 256, 0, stream>>>(node, A, Bm, prj, H);
  }
  k_blk_mfma<<<dim3(KN, BS / 64, BH / 64), 256, 0, stream>>>(Hno, Hna, node, rew, blkW, blkb, out);
}

// Round 3
// 665.533 us; speedup vs baseline: 3.1135x; 1.2982x over previous
//
#include <hip/hip_runtime.h>
#include <math.h>

#define BS 256
#define LQ 256
#define KN 64
#define BH 512
#define SUB_IN 1537

typedef __attribute__((ext_vector_type(8))) short bf16x8;
typedef __attribute__((ext_vector_type(4))) float f32x4;

__device__ __forceinline__ float clip15(float x) {
  return fminf(fmaxf(x, -15.f), 15.f);
}
__device__ __forceinline__ short f2bf(float f) {
  unsigned u = __float_as_uint(f);
  u = u + 0x7fffu + ((u >> 16) & 1u);
  return (short)(u >> 16);
}
__device__ __forceinline__ float bf2f(short s) {
  return __uint_as_float(((unsigned)(unsigned short)s) << 16);
}

// XOR swizzle on the 16B slot within each 128B LDS row (proven in R2)
#define SWZ(row, byte) ((byte) ^ (((((row) ^ ((row) >> 3)) & 7)) << 4))

// ---------------- small prep kernels ----------------

__global__ void k_cvt(const float* __restrict__ in, short* __restrict__ out, int n4) {
  int i = blockIdx.x * blockDim.x + threadIdx.x;
  if (i >= n4) return;
  f32x4 v = ((const f32x4*)in)[i];
  ((short4*)out)[i] = make_short4(f2bf(v[0]), f2bf(v[1]), f2bf(v[2]), f2bf(v[3]));
}

__global__ void k_cvt_scaled(const float* __restrict__ in, const float* __restrict__ w,
                             short* __restrict__ out, int n4) {
  int i = blockIdx.x * blockDim.x + threadIdx.x;
  if (i >= n4) return;
  int d4 = i & (BH / 4 - 1);
  f32x4 v = ((const f32x4*)in)[i];
  f32x4 wv = ((const f32x4*)w)[d4];
  v = v * wv;
  ((short4*)out)[i] = make_short4(f2bf(v[0]), f2bf(v[1]), f2bf(v[2]), f2bf(v[3]));
}

// prjT[n][k] = bf16(prj[k][n]); k=2048, n=512
__global__ void k_prjT(const float* __restrict__ prj, short* __restrict__ prjT) {
  __shared__ float t[32][33];
  int k0 = blockIdx.x * 32, n0 = blockIdx.y * 32;
  int x = threadIdx.x & 31, y = threadIdx.x >> 5;  // 32x8
  for (int yy = y; yy < 32; yy += 8)
    t[yy][x] = prj[(size_t)(k0 + yy) * BH + n0 + x];
  __syncthreads();
  for (int yy = y; yy < 32; yy += 8)
    prjT[(size_t)(n0 + yy) * 2048 + k0 + x] = f2bf(t[x][yy]);
}

__global__ void k_rowdot(const float* __restrict__ X, const float* __restrict__ w,
                         float* __restrict__ out, int rows) {
  int row = blockIdx.x * 4 + (threadIdx.x >> 6);
  int lane = threadIdx.x & 63;
  if (row >= rows) return;
  const float* x = X + (size_t)row * BH;
  float s = 0.f;
#pragma unroll
  for (int i = 0; i < BH; i += 64) s = fmaf(x[i + lane], w[i + lane], s);
#pragma unroll
  for (int off = 32; off; off >>= 1) s += __shfl_down(s, off);
  if (lane == 0) out[row] = s;
}

// ---------------- staging helpers (64x64 bf16 tile into SWZ'd LDS) ----------------

// natural [row][k] bf16 source, row stride ld elems
__device__ __forceinline__ void stage_nat(const short* __restrict__ src, size_t ld,
                                          short* As, int tid) {
  int kl = (tid & 15) * 4;
#pragma unroll
  for (int it = 0; it < 4; ++it) {
    int row = (tid >> 4) + it * 16;
    short4 v = *(const short4*)(src + (size_t)row * ld + kl);
    *(short4*)((char*)As + SWZ(row, row * 128 + kl * 2)) = v;
  }
}

// natural [row][k] f32 source with convert
__device__ __forceinline__ void stage_nat_f32(const float* __restrict__ src, size_t ld,
                                              short* As, int tid) {
  int kl = (tid & 15) * 4;
#pragma unroll
  for (int it = 0; it < 4; ++it) {
    int row = (tid >> 4) + it * 16;
    f32x4 v = *(const f32x4*)(src + (size_t)row * ld + kl);
    *(short4*)((char*)As + SWZ(row, row * 128 + kl * 2)) =
        make_short4(f2bf(v[0]), f2bf(v[1]), f2bf(v[2]), f2bf(v[3]));
  }
}

// transposed: bf16 source [k][n] (stride ld) -> Bs[n][k]
__device__ __forceinline__ void stage_tr(const short* __restrict__ src, size_t ld,
                                         short* Bs, int tid) {
  int n0 = (tid & 15) * 4;
  int k0 = (tid >> 4) * 4;
  short4 r0 = *(const short4*)(src + (size_t)(k0 + 0) * ld + n0);
  short4 r1 = *(const short4*)(src + (size_t)(k0 + 1) * ld + n0);
  short4 r2 = *(const short4*)(src + (size_t)(k0 + 2) * ld + n0);
  short4 r3 = *(const short4*)(src + (size_t)(k0 + 3) * ld + n0);
  *(short4*)((char*)Bs + SWZ(n0 + 0, (n0 + 0) * 128 + k0 * 2)) = make_short4(r0.x, r1.x, r2.x, r3.x);
  *(short4*)((char*)Bs + SWZ(n0 + 1, (n0 + 1) * 128 + k0 * 2)) = make_short4(r0.y, r1.y, r2.y, r3.y);
  *(short4*)((char*)Bs + SWZ(n0 + 2, (n0 + 2) * 128 + k0 * 2)) = make_short4(r0.z, r1.z, r2.z, r3.z);
  *(short4*)((char*)Bs + SWZ(n0 + 3, (n0 + 3) * 128 + k0 * 2)) = make_short4(r0.w, r1.w, r2.w, r3.w);
}

// transposed: f32 source [k][n] (stride ld) -> Bs[n][k] with convert (proven R2)
__device__ __forceinline__ void stage_tr_f32(const float* __restrict__ src, size_t ld,
                                             short* Bs, int tid) {
  int n0 = (tid & 15) * 4;
  int k0 = (tid >> 4) * 4;
  f32x4 r0 = *(const f32x4*)(src + (size_t)(k0 + 0) * ld + n0);
  f32x4 r1 = *(const f32x4*)(src + (size_t)(k0 + 1) * ld + n0);
  f32x4 r2 = *(const f32x4*)(src + (size_t)(k0 + 2) * ld + n0);
  f32x4 r3 = *(const f32x4*)(src + (size_t)(k0 + 3) * ld + n0);
#pragma unroll
  for (int j = 0; j < 4; ++j) {
    int n = n0 + j;
    *(short4*)((char*)Bs + SWZ(n, n * 128 + k0 * 2)) =
        make_short4(f2bf(r0[j]), f2bf(r1[j]), f2bf(r2[j]), f2bf(r3[j]));
  }
}

// wave computes 16 rows (m0..m0+15) x 64 cols of a 64x64 tile
__device__ __forceinline__ void mfma64(const short* As, const short* Bs,
                                       f32x4 acc[4], int lane, int m0) {
#pragma unroll
  for (int kb = 0; kb < 2; ++kb) {
    int k16 = kb * 32 + (lane >> 4) * 8;
    int arow = m0 + (lane & 15);
    bf16x8 af = *(const bf16x8*)((const char*)As + SWZ(arow, arow * 128 + k16 * 2));
#pragma unroll
    for (int f = 0; f < 4; ++f) {
      int nrow = f * 16 + (lane & 15);
      bf16x8 bfr = *(const bf16x8*)((const char*)Bs + SWZ(nrow, nrow * 128 + k16 * 2));
      acc[f] = __builtin_amdgcn_mfma_f32_16x16x32_bf16(af, bfr, acc[f], 0, 0, 0);
    }
  }
}

// ---------------- MFMA pipeline kernels ----------------

// S[b,c,q] = sum_d Cw[c,d]*Q[q,d] + cw[c] + qw[q] + bias
__global__ void k_score_mfma(const short* __restrict__ Cw, const float* __restrict__ Q,
                             const float* __restrict__ cw, const float* __restrict__ qw,
                             const float* __restrict__ bias, float* __restrict__ S) {
  const int b = blockIdx.x, q0 = blockIdx.y * 64;
  const int tid = threadIdx.x, lane = tid & 63, m0 = (tid >> 6) * 16;
  __shared__ __align__(16) short As[2][64 * 64];
  __shared__ __align__(16) short Bs[2][64 * 64];
  f32x4 acc[4] = {};
  const short* Cb = Cw + (size_t)b * KN * BH;
  const float* Qb = Q + ((size_t)b * LQ + q0) * BH;
  for (int kk = 0; kk < BH; kk += 128) {
    stage_nat(Cb + kk, BH, As[0], tid);
    stage_nat(Cb + kk + 64, BH, As[1], tid);
    stage_nat_f32(Qb + kk, BH, Bs[0], tid);
    stage_nat_f32(Qb + kk + 64, BH, Bs[1], tid);
    __syncthreads();
    mfma64(As[0], Bs[0], acc, lane, m0);
    mfma64(As[1], Bs[1], acc, lane, m0);
    __syncthreads();
  }
  float bv = bias[0];
#pragma unroll
  for (int f = 0; f < 4; ++f) {
    int q = q0 + f * 16 + (lane & 15);
    float qv = qw[b * LQ + q] + bv;
#pragma unroll
    for (int e = 0; e < 4; ++e) {
      int c = m0 + (lane >> 4) * 4 + e;
      S[((size_t)b * KN + c) * LQ + q] = acc[f][e] + cw[b * KN + c] + qv;
    }
  }
}

__global__ void k_softmax_q(const float* __restrict__ S, const float* __restrict__ qmask,
                            short* __restrict__ S1) {
  int row = blockIdx.x * 4 + (threadIdx.x >> 6);
  int lane = threadIdx.x & 63;
  int b = row >> 6;
  const float4* Sr = (const float4*)(S + (size_t)row * LQ);
  const float4* Qm = (const float4*)(qmask + (size_t)b * LQ);
  float4 xv = Sr[lane];
  float4 mv = Qm[lane];
  float xa[4] = {xv.x, xv.y, xv.z, xv.w};
  float ma[4] = {mv.x, mv.y, mv.z, mv.w};
  float m = -1e30f;
#pragma unroll
  for (int j = 0; j < 4; ++j) { xa[j] = clip15(xa[j]) * ma[j]; m = fmaxf(m, xa[j]); }
#pragma unroll
  for (int off = 32; off; off >>= 1) m = fmaxf(m, __shfl_xor(m, off));
  float s = 0.f;
#pragma unroll
  for (int j = 0; j < 4; ++j) { xa[j] = __expf(xa[j] - m) * ma[j]; s += xa[j]; }
#pragma unroll
  for (int off = 32; off; off >>= 1) s += __shfl_xor(s, off);
  float inv = 1.f / (s + 1e-6f);
  *(short4*)(S1 + (size_t)row * LQ + lane * 4) =
      make_short4(f2bf(xa[0] * inv), f2bf(xa[1] * inv), f2bf(xa[2] * inv), f2bf(xa[3] * inv));
}

__global__ void k_softmax_c(const float* __restrict__ S, const float* __restrict__ cmask,
                            short* __restrict__ S2) {
  int b = blockIdx.x;
  int q = threadIdx.x;
  const float* Sb = S + (size_t)b * KN * LQ + q;
  const float* cm = cmask + b * KN;
  float m = -1e30f;
  for (int c = 0; c < KN; ++c) {
    float x = clip15(Sb[(size_t)c * LQ]) * cm[c];
    m = fmaxf(m, x);
  }
  float sum = 0.f;
  for (int c = 0; c < KN; ++c) {
    float mk = cm[c];
    float x = clip15(Sb[(size_t)c * LQ]) * mk;
    sum += __expf(x - m) * mk;
  }
  float inv = 1.f / (sum + 1e-6f);
  for (int c = 0; c < KN; ++c) {
    float mk = cm[c];
    float x = clip15(Sb[(size_t)c * LQ]) * mk;
    S2[((size_t)b * KN + c) * LQ + q] = f2bf(__expf(x - m) * mk * inv);
  }
}

// A[c,d] = sum_q S1[c,q] Q[q,d]; epilogue writes A_bf and CA_bf = node*A
__global__ void k_gemm_A_mfma(const short* __restrict__ S1, const float* __restrict__ Q,
                              const short* __restrict__ node_bf,
                              short* __restrict__ A_bf, short* __restrict__ CA_bf) {
  const int b = blockIdx.x, d0 = blockIdx.y * 64;
  const int tid = threadIdx.x, lane = tid & 63, m0 = (tid >> 6) * 16;
  __shared__ __align__(16) short As[64 * 64];
  __shared__ __align__(16) short Bs[64 * 64];
  f32x4 acc[4] = {};
  const short* S1b = S1 + (size_t)b * KN * LQ;
  const float* Qb = Q + (size_t)b * LQ * BH;
  for (int kk = 0; kk < LQ; kk += 64) {
    stage_nat(S1b + kk, LQ, As, tid);
    stage_tr_f32(Qb + (size_t)kk * BH + d0, BH, Bs, tid);
    __syncthreads();
    mfma64(As, Bs, acc, lane, m0);
    __syncthreads();
  }
  const short* nb = node_bf + (size_t)b * KN * BH;
#pragma unroll
  for (int f = 0; f < 4; ++f) {
    int d = d0 + f * 16 + (lane & 15);
#pragma unroll
    for (int e = 0; e < 4; ++e) {
      int c = m0 + (lane >> 4) * 4 + e;
      size_t gi = ((size_t)b * KN + c) * BH + d;
      float av = acc[f][e];
      A_bf[gi] = f2bf(av);
      CA_bf[gi] = f2bf(bf2f(nb[(size_t)c * BH + d]) * av);
    }
  }
}

// T[c,k2] = sum_q S1[c,q] S2[k2,q]
__global__ void k_gemm_T_mfma(const short* __restrict__ S1, const short* __restrict__ S2,
                              short* __restrict__ T) {
  const int b = blockIdx.x;
  const int tid = threadIdx.x, lane = tid & 63, m0 = (tid >> 6) * 16;
  __shared__ __align__(16) short As[64 * 64];
  __shared__ __align__(16) short Bs[64 * 64];
  f32x4 acc[4] = {};
  const short* S1b = S1 + (size_t)b * KN * LQ;
  const short* S2b = S2 + (size_t)b * KN * LQ;
  for (int kk = 0; kk < LQ; kk += 64) {
    stage_nat(S1b + kk, LQ, As, tid);
    stage_nat(S2b + kk, LQ, Bs, tid);
    __syncthreads();
    mfma64(As, Bs, acc, lane, m0);
    __syncthreads();
  }
#pragma unroll
  for (int f = 0; f < 4; ++f) {
    int k2 = f * 16 + (lane & 15);
#pragma unroll
    for (int e = 0; e < 4; ++e) {
      int c = m0 + (lane >> 4) * 4 + e;
      T[((size_t)b * KN + c) * KN + k2] = f2bf(acc[f][e]);
    }
  }
}

// Bm[c,d] = sum_k T[c,k] node[k,d]; writes CB_bf = node*Bm
__global__ void k_gemm_B_mfma(const short* __restrict__ T, const short* __restrict__ node_bf,
                              short* __restrict__ CB_bf) {
  const int b = blockIdx.x, d0 = blockIdx.y * 64;
  const int tid = threadIdx.x, lane = tid & 63, m0 = (tid >> 6) * 16;
  __shared__ __align__(16) short As[64 * 64];
  __shared__ __align__(16) short Bs[64 * 64];
  f32x4 acc[4] = {};
  const short* nb = node_bf + (size_t)b * KN * BH;
  stage_nat(T + (size_t)b * KN * KN, KN, As, tid);
  stage_tr(nb + d0, BH, Bs, tid);
  __syncthreads();
  mfma64(As, Bs, acc, lane, m0);
#pragma unroll
  for (int f = 0; f < 4; ++f) {
    int d = d0 + f * 16 + (lane & 15);
#pragma unroll
    for (int e = 0; e < 4; ++e) {
      int c = m0 + (lane >> 4) * 4 + e;
      CB_bf[((size_t)b * KN + c) * BH + d] = f2bf(bf2f(nb[(size_t)c * BH + d]) * acc[f][e]);
    }
  }
}

// H[c,o] = sum_j feat[c,j]*prjT[o,j]; feat segs {node, A, CA, CB}
__global__ void k_proj_mfma(const short* __restrict__ node_bf, const short* __restrict__ A_bf,
                            const short* __restrict__ CA_bf, const short* __restrict__ CB_bf,
                            const short* __restrict__ prjT, short* __restrict__ H) {
  const int b = blockIdx.x, o0 = blockIdx.y * 64;
  const int tid = threadIdx.x, lane = tid & 63, m0 = (tid >> 6) * 16;
  __shared__ __align__(16) short As[2][64 * 64];
  __shared__ __align__(16) short Bs[2][64 * 64];
  f32x4 acc[4] = {};
  size_t boff = (size_t)b * KN * BH;
  const short* segp[4] = {node_bf + boff, A_bf + boff, CA_bf + boff, CB_bf + boff};
  const short* pT = prjT + (size_t)o0 * 2048;
  for (int kk = 0; kk < 4 * BH; kk += 128) {
#pragma unroll
    for (int h = 0; h < 2; ++h) {
      int k2 = kk + h * 64;
      stage_nat(segp[k2 >> 9] + (k2 & 511), BH, As[h], tid);
      stage_nat(pT + k2, 2048, Bs[h], tid);
    }
    __syncthreads();
    mfma64(As[0], Bs[0], acc, lane, m0);
    mfma64(As[1], Bs[1], acc, lane, m0);
    __syncthreads();
  }
#pragma unroll
  for (int f = 0; f < 4; ++f) {
    int o = o0 + f * 16 + (lane & 15);
#pragma unroll
    for (int e = 0; e < 4; ++e) {
      int c = m0 + (lane >> 4) * 4 + e;
      H[((size_t)b * KN + c) * BH + o] = f2bf(acc[f][e]);
    }
  }
}

// out[b,kb,o] = sum_s x[b,kb,s] W[kb,s,o] + rew[b]*W[kb,1536,o] + bias[kb,o]
// tile: 128 batches x 128 outputs per block; W staged transposed+cvt from f32
__global__ void k_blk_mfma(const short* __restrict__ Hno, const short* __restrict__ Hna,
                           const short* __restrict__ node_bf, const float* __restrict__ rew,
                           const float* __restrict__ W, const float* __restrict__ bias,
                           float* __restrict__ out) {
  const int kb = blockIdx.x;
  const int b0 = blockIdx.y * 128;
  const int o0 = blockIdx.z * 128;
  const int tid = threadIdx.x, lane = tid & 63, m0 = (tid >> 6) * 32;
  __shared__ __align__(16) short As[128 * 64];
  __shared__ __align__(16) short Bs[128 * 64];  // Bs[n=128][k=64]
  f32x4 acc[16] = {};
  const float* Wk = W + (size_t)kb * SUB_IN * BH;
  const short* segs[3] = {Hno, Hna, node_bf};
  for (int kk = 0; kk < 1536; kk += 64) {
    const short* src = segs[kk >> 9] + (size_t)kb * BH + (kk & 511);
    // A: 128 rows (batch) x 64 k
    {
      int kl = (tid & 15) * 4;
#pragma unroll
      for (int it = 0; it < 8; ++it) {
        int row = (tid >> 4) + it * 16;
        short4 v = *(const short4*)(src + (size_t)(b0 + row) * KN * BH + kl);
        *(short4*)((char*)As + SWZ(row, row * 128 + kl * 2)) = v;
      }
    }
    // B: W[kk..kk+63][o0..o0+127] -> Bs[n][k]
    {
      int n0 = (tid & 31) * 4;
      int k0 = (tid >> 5) * 8;
      f32x4 r[8];
#pragma unroll
      for (int j = 0; j < 8; ++j)
        r[j] = *(const f32x4*)(Wk + (size_t)(kk + k0 + j) * BH + o0 + n0);
#pragma unroll
      for (int j2 = 0; j2 < 4; ++j2) {
        int n = n0 + j2;
        bf16x8 cv;
#pragma unroll
        for (int j = 0; j < 8; ++j) cv[j] = f2bf(r[j][j2]);
        *(bf16x8*)((char*)Bs + SWZ(n, n * 128 + k0 * 2)) = cv;
      }
    }
    __syncthreads();
#pragma unroll
    for (int kb2 = 0; kb2 < 2; ++kb2) {
      int k16 = kb2 * 32 + (lane >> 4) * 8;
#pragma unroll
      for (int mi = 0; mi < 2; ++mi) {
        int arow = m0 + mi * 16 + (lane & 15);
        bf16x8 af = *(const bf16x8*)((const char*)As + SWZ(arow, arow * 128 + k16 * 2));
#pragma unroll
        for (int f = 0; f < 8; ++f) {
          int nrow = f * 16 + (lane & 15);
          bf16x8 bfr = *(const bf16x8*)((const char*)Bs + SWZ(nrow, nrow * 128 + k16 * 2));
          acc[mi * 8 + f] = __builtin_amdgcn_mfma_f32_16x16x32_bf16(af, bfr, acc[mi * 8 + f], 0, 0, 0);
        }
      }
    }
    __syncthreads();
  }
#pragma unroll
  for (int mi = 0; mi < 2; ++mi) {
#pragma unroll
    for (int f = 0; f < 8; ++f) {
      int o = o0 + f * 16 + (lane & 15);
      float wr = Wk[(size_t)1536 * BH + o];
      float bv = bias[kb * BH + o];
#pragma unroll
      for (int e = 0; e < 4; ++e) {
        int bb = b0 + m0 + mi * 16 + (lane >> 4) * 4 + e;
        out[((size_t)bb * KN + kb) * BH + o] = acc[mi * 8 + f][e] + rew[bb] * wr + bv;
      }
    }
  }
}

extern "C" void kernel_launch(void* const* d_in, const int* in_sizes, int n_in,
                              void* d_out, int out_size, void* d_ws, size_t ws_size,
                              hipStream_t stream) {
  (void)in_sizes; (void)n_in; (void)out_size; (void)ws_size;
  const float* act   = (const float*)d_in[0];
  const float* obs   = (const float*)d_in[1];
  const float* amask = (const float*)d_in[2];
  const float* omask = (const float*)d_in[3];
  const float* rew   = (const float*)d_in[4];
  const float* node  = (const float*)d_in[5];
  const float* nmask = (const float*)d_in[6];
  const float* w4C_o = (const float*)d_in[7];
  const float* w4Q_o = (const float*)d_in[8];
  const float* w4m_o = (const float*)d_in[9];
  const float* bias_o= (const float*)d_in[10];
  const float* w4C_a = (const float*)d_in[11];
  const float* w4Q_a = (const float*)d_in[12];
  const float* w4m_a = (const float*)d_in[13];
  const float* bias_a= (const float*)d_in[14];
  const float* prj_o = (const float*)d_in[15];
  const float* prj_a = (const float*)d_in[16];
  const float* blkW  = (const float*)d_in[17];
  const float* blkb  = (const float*)d_in[18];
  float* out = (float*)d_out;

  char* wsb = (char*)d_ws;
  auto alloc = [&](size_t bytes) { char* p = wsb; wsb += (bytes + 255) & ~255ull; return p; };
  const size_t NKB = (size_t)BS * KN * BH;  // 8.4M elems
  short* node_bf = (short*)alloc(NKB * 2);
  short* CwCA    = (short*)alloc(NKB * 2);              // Cw during score; CA after gemm_A
  short* prjT    = (short*)alloc((size_t)2048 * BH * 2);
  float* S       = (float*)alloc((size_t)BS * KN * LQ * 4);  // aliased as CB after softmaxes
  short* CB      = (short*)S;
  short* S1      = (short*)alloc((size_t)BS * KN * LQ * 2);
  short* S2      = (short*)alloc((size_t)BS * KN * LQ * 2);
  short* A_bf    = (short*)alloc(NKB * 2);
  short* T_bf    = (short*)alloc((size_t)BS * KN * KN * 2);
  short* Hno     = (short*)alloc(NKB * 2);
  short* Hna     = (short*)alloc(NKB * 2);
  float* cw      = (float*)alloc((size_t)BS * KN * 4);
  float* qw      = (float*)alloc((size_t)BS * LQ * 4);

  k_cvt<<<dim3((int)(NKB / 4 / 256)), 256, 0, stream>>>(node, node_bf, (int)(NKB / 4));

  for (int head = 0; head < 2; ++head) {
    const float* Qseq  = head ? act : obs;
    const float* qmask = head ? amask : omask;
    const float* w4C   = head ? w4C_a : w4C_o;
    const float* w4Q   = head ? w4Q_a : w4Q_o;
    const float* w4m   = head ? w4m_a : w4m_o;
    const float* bias  = head ? bias_a : bias_o;
    const float* prj   = head ? prj_a : prj_o;
    short* H = head ? Hna : Hno;

    k_cvt_scaled<<<dim3((int)(NKB / 4 / 256)), 256, 0, stream>>>(node, w4m, CwCA, (int)(NKB / 4));
    k_prjT<<<dim3(64, 16), 256, 0, stream>>>(prj, prjT);
    k_rowdot<<<dim3(BS * KN / 4), 256, 0, stream>>>(node, w4C, cw, BS * KN);
    k_rowdot<<<dim3(BS * LQ / 4), 256, 0, stream>>>(Qseq, w4Q, qw, BS * LQ);
    k_score_mfma<<<dim3(BS, LQ / 64), 256, 0, stream>>>(CwCA, Qseq, cw, qw, bias, S);
    k_softmax_c<<<dim3(BS), 256, 0, stream>>>(S, nmask, S2);
    k_softmax_q<<<dim3(BS * KN / 4), 256, 0, stream>>>(S, qmask, S1);
    k_gemm_A_mfma<<<dim3(BS, BH / 64), 256, 0, stream>>>(S1, Qseq, node_bf, A_bf, CwCA);
    k_gemm_T_mfma<<<dim3(BS), 256, 0, stream>>>(S1, S2, T_bf);
    k_gemm_B_mfma<<<dim3(BS, BH / 64), 256, 0, stream>>>(T_bf, node_bf, CB);
    k_proj_mfma<<<dim3(BS, BH / 64), 256, 0, stream>>>(node_bf, A_bf, CwCA, CB, prjT, H);
  }
  k_blk_mfma<<<dim3(KN, BS / 128, BH / 128), 256, 0, stream>>>(Hno, Hna, node_bf, rew, blkW, blkb, out);
}